// Round 10
// baseline (332.764 us; speedup 1.0000x reference)
//
#include <hip/hip_runtime.h>
#include <math.h>

// ---------------------------------------------------------------------------
// GraphTransformerLayer N=50000, E=640000, D=128, H=8, DH=16  (gfx950)
// Round 10: round-9 pipeline +
//   - K/V stored fp8 e4m3 (HW cvt pack in QKV epilogue, cvt decode in attn)
//     -> gather bytes halve (attn was fetch-bound at 148 MB / 2.9 TB/s)
//   - h-cast fused into QKV: A-fragments built in registers from fp32 h,
//     reused across Q/K/V GEMMs (kills hb buffer: -51 MB traffic, -1 launch)
//
// Fragment order for an MxK slab (M=128, K=KB*32):
//   elem index = ((kb*8 + mtile)*64 + lane)*8 + j
//   row = mtile*16 + (lane&15),  col = kb*32 + (lane>>4)*8 + j
// Swapped-operand MFMA: mfma(Wfrag, hfrag) -> C^T: row = m*16+(lane&15),
// cols = w*32+nt*16+quad*4+{0..3} contiguous.
// ---------------------------------------------------------------------------

#define ND128 16384
typedef _Float16 f16;
typedef __attribute__((ext_vector_type(8))) _Float16 h8;
typedef __attribute__((ext_vector_type(4))) _Float16 h4;
typedef __attribute__((ext_vector_type(2))) _Float16 h2;
typedef __attribute__((ext_vector_type(4))) float f4;
typedef __attribute__((ext_vector_type(2))) float ff2;

__device__ __forceinline__ ff2 fp8x2_dec(unsigned v) {
#if __has_builtin(__builtin_amdgcn_cvt_pk_f32_fp8)
    return __builtin_amdgcn_cvt_pk_f32_fp8((int)v, false);
#else
    ff2 r;
    unsigned b0 = v & 0xffu, b1 = (v >> 8) & 0xffu;
    {
        unsigned e = (b0 >> 3) & 15u, m = b0 & 7u;
        float x = e ? __uint_as_float(((e + 120u) << 23) | (m << 20)) : (float)m * 0.001953125f;
        r.x = (b0 & 0x80u) ? -x : x;
    }
    {
        unsigned e = (b1 >> 3) & 15u, m = b1 & 7u;
        float x = e ? __uint_as_float(((e + 120u) << 23) | (m << 20)) : (float)m * 0.001953125f;
        r.y = (b1 & 0x80u) ? -x : x;
    }
    return r;
#endif
}

#if !__has_builtin(__builtin_amdgcn_cvt_pk_fp8_f32)
__device__ __forceinline__ unsigned char fp8_1(float f) {
    float a = fabsf(f);
    unsigned sg = (__float_as_uint(f) >> 31) << 7;
    if (a >= 448.f) return (unsigned char)(sg | 0x7E);
    if (a < 0.0009765625f) return (unsigned char)sg;
    int E; float m = frexpf(a, &E);          // a = m*2^E, m in [0.5,1)
    if (E - 1 < -6) {
        int q = (int)rintf(a * 512.f);
        if (q > 7) return (unsigned char)(sg | 0x08);
        return (unsigned char)(sg | q);
    }
    int q = (int)rintf(m * 16.f);
    if (q == 16) { q = 8; E += 1; }
    int Ef = E - 1 + 7;
    if (Ef > 15) return (unsigned char)(sg | 0x7E);
    return (unsigned char)(sg | (Ef << 3) | (q - 8));
}
#endif

__device__ __forceinline__ unsigned fp8_pack4(float a0, float a1, float a2, float a3) {
#if __has_builtin(__builtin_amdgcn_cvt_pk_fp8_f32)
    int pk = __builtin_amdgcn_cvt_pk_fp8_f32(a0, a1, 0, false);
    pk = __builtin_amdgcn_cvt_pk_fp8_f32(a2, a3, pk, true);
    return (unsigned)pk;
#else
    return (unsigned)fp8_1(a0) | ((unsigned)fp8_1(a1) << 8) |
           ((unsigned)fp8_1(a2) << 16) | ((unsigned)fp8_1(a3) << 24);
#endif
}

// --- prep: cast weights -> f16 frag order; block 0 zeroes bn. --------------
__global__ __launch_bounds__(256) void k_prep(
    const float* __restrict__ WQ, const float* __restrict__ WK,
    const float* __restrict__ WV, const float* __restrict__ WO,
    const float* __restrict__ W2,
    f16* __restrict__ Wqb, f16* __restrict__ Wkb,
    f16* __restrict__ Wvb, f16* __restrict__ Wob, f16* __restrict__ W2b,
    float* __restrict__ bn)
{
    const int b = blockIdx.x, tid = threadIdx.x;
    if (b == 0) { bn[tid] = 0.f; bn[tid + 256] = 0.f; }
    const float* Wsrc; f16* dst; int K, base;
    if (b < 4) {
        Wsrc = b == 0 ? WQ : b == 1 ? WK : b == 2 ? WV : WO;
        dst  = b == 0 ? Wqb : b == 1 ? Wkb : b == 2 ? Wvb : Wob;
        K = 128; base = 0;
    } else {
        Wsrc = W2; dst = W2b; K = 256; base = (b - 4) * 2048;
    }
#pragma unroll
    for (int it = 0; it < 8; ++it) {
        int cid = base + it * 256 + tid;
        int lane = cid & 63;
        int kb, nt;
        if (K == 128) { kb = (cid >> 6) & 3; nt = cid >> 8; }
        else          { kb = (cid >> 6) & 7; nt = cid >> 9; }
        int row = nt * 16 + (lane & 15);
        int col = kb * 32 + (lane >> 4) * 8;
        const float* p = Wsrc + (size_t)row * K + col;
        f16 o8[8];
#pragma unroll
        for (int j = 0; j < 8; ++j) o8[j] = (f16)p[j];
        *(h8*)(dst + (size_t)cid * 8) = *(const h8*)o8;
    }
}

// --- QKV fused: A-frags from fp32 h in registers, 3 GEMMs, Q f16 / K,V fp8.
// Also zeroes this slab's cursor slice. -------------------------------------
__global__ __launch_bounds__(256) void k_qkvF(
    const float* __restrict__ h,
    const f16* __restrict__ Wqb, const f16* __restrict__ Wkb, const f16* __restrict__ Wvb,
    f16* __restrict__ Qb, unsigned char* __restrict__ Kb8, unsigned char* __restrict__ Vb8,
    int* __restrict__ cursor, int N)
{
    const int slab = blockIdx.x, tid = threadIdx.x;
    const int w = tid >> 6, lane = tid & 63;
    const int rl = lane & 15, quad = lane >> 4;
    if (tid < 128) {
        int ci = slab * 128 + tid;
        if (ci < N) cursor[ci] = 0;
    }

    // A fragments: row = slab*128 + m*16 + rl, cols kb*32 + quad*8 + {0..7}
    h8 afr[8][4];
#pragma unroll
    for (int m = 0; m < 8; ++m) {
        int row = slab * 128 + m * 16 + rl;
#pragma unroll
        for (int kb = 0; kb < 4; ++kb) {
            h8 a;
            if (row < N) {
                const float* p = h + (size_t)row * 128 + kb * 32 + quad * 8;
                float4 f0 = *(const float4*)p;
                float4 f1 = *(const float4*)(p + 4);
                a[0] = (f16)f0.x; a[1] = (f16)f0.y; a[2] = (f16)f0.z; a[3] = (f16)f0.w;
                a[4] = (f16)f1.x; a[5] = (f16)f1.y; a[6] = (f16)f1.z; a[7] = (f16)f1.w;
            } else {
#pragma unroll
                for (int j = 0; j < 8; ++j) a[j] = (f16)0.f;
            }
            afr[m][kb] = a;
        }
    }

    for (int oidx = 0; oidx < 3; ++oidx) {
        const f16* __restrict__ Wb = oidx == 0 ? Wqb : oidx == 1 ? Wkb : Wvb;
        h8 bfr[2][4];
#pragma unroll
        for (int nt = 0; nt < 2; ++nt)
#pragma unroll
            for (int kb = 0; kb < 4; ++kb)
                bfr[nt][kb] = *(const h8*)(Wb + (size_t)(((2 * w + nt) * 4 + kb) * 64 + lane) * 8);

        f4 acc[8][2];
        f4 zero = {0.f, 0.f, 0.f, 0.f};
#pragma unroll
        for (int m = 0; m < 8; ++m) { acc[m][0] = zero; acc[m][1] = zero; }
#pragma unroll
        for (int m = 0; m < 8; ++m)
#pragma unroll
            for (int kb = 0; kb < 4; ++kb) {
                acc[m][0] = __builtin_amdgcn_mfma_f32_16x16x32_f16(bfr[0][kb], afr[m][kb], acc[m][0], 0, 0, 0);
                acc[m][1] = __builtin_amdgcn_mfma_f32_16x16x32_f16(bfr[1][kb], afr[m][kb], acc[m][1], 0, 0, 0);
            }

        if (oidx == 0) {
#pragma unroll
            for (int m = 0; m < 8; ++m) {
                int gr = slab * 128 + m * 16 + rl;
                if (gr < N) {
#pragma unroll
                    for (int nt = 0; nt < 2; ++nt) {
                        h4 o;
                        o[0] = (f16)acc[m][nt][0]; o[1] = (f16)acc[m][nt][1];
                        o[2] = (f16)acc[m][nt][2]; o[3] = (f16)acc[m][nt][3];
                        *(h4*)(Qb + (size_t)gr * 128 + w * 32 + nt * 16 + quad * 4) = o;
                    }
                }
            }
        } else {
            unsigned char* __restrict__ O8 = oidx == 1 ? Kb8 : Vb8;
#pragma unroll
            for (int m = 0; m < 8; ++m) {
                int gr = slab * 128 + m * 16 + rl;
                if (gr < N) {
#pragma unroll
                    for (int nt = 0; nt < 2; ++nt) {
                        unsigned pk = fp8_pack4(acc[m][nt][0], acc[m][nt][1],
                                                acc[m][nt][2], acc[m][nt][3]);
                        *(unsigned*)(O8 + (size_t)gr * 128 + w * 32 + nt * 16 + quad * 4) = pk;
                    }
                }
            }
        }
    }
}

// --- CSR build -------------------------------------------------------------
__global__ __launch_bounds__(256) void k_hist(
    const int* __restrict__ dst, int* __restrict__ cursor, int E)
{
    int e = blockIdx.x * 256 + threadIdx.x;
    if (e < E) atomicAdd(&cursor[dst[e]], 1);
}

__global__ __launch_bounds__(256) void k_scanA(
    const int* __restrict__ cnt, int* __restrict__ bsum, int N)
{
    const int t = threadIdx.x;
    int base = blockIdx.x * 2048 + t * 8;
    int s = 0;
#pragma unroll
    for (int j = 0; j < 8; ++j) {
        int idx = base + j;
        if (idx < N) s += cnt[idx];
    }
#pragma unroll
    for (int off = 32; off; off >>= 1) s += __shfl_down(s, off, 64);
    __shared__ int ws4[4];
    if ((t & 63) == 0) ws4[t >> 6] = s;
    __syncthreads();
    if (t == 0) bsum[blockIdx.x] = ws4[0] + ws4[1] + ws4[2] + ws4[3];
}

__global__ __launch_bounds__(256) void k_scanC(
    const int* __restrict__ cnt, const int* __restrict__ bsum,
    int* __restrict__ rowptr, int* __restrict__ cursor, int N, int nsb)
{
    const int t = threadIdx.x, b = blockIdx.x;
    __shared__ int sboff;
    if (t == 0) {
        int r = 0;
        for (int i2 = 0; i2 < b; ++i2) r += bsum[i2];
        sboff = r;
    }
    if (t == 64 && b == nsb - 1) {
        int r = 0;
        for (int i2 = 0; i2 < nsb; ++i2) r += bsum[i2];
        rowptr[N] = r;
    }
    int base = b * 2048 + t * 8;
    int loc[8];
    int s = 0;
#pragma unroll
    for (int j = 0; j < 8; ++j) {
        int idx = base + j;
        loc[j] = (idx < N) ? cnt[idx] : 0;
        s += loc[j];
    }
    __shared__ int part[256];
    part[t] = s;
    __syncthreads();
    for (int off = 1; off < 256; off <<= 1) {
        int v = (t >= off) ? part[t - off] : 0;
        __syncthreads();
        part[t] += v;
        __syncthreads();
    }
    int run = sboff + (t ? part[t - 1] : 0);
#pragma unroll
    for (int j = 0; j < 8; ++j) {
        int idx = base + j;
        if (idx < N) { rowptr[idx] = run; cursor[idx] = run; run += loc[j]; }
    }
}

__global__ __launch_bounds__(256) void k_scatter(
    const int* __restrict__ src, const int* __restrict__ dst,
    int* __restrict__ cursor, int* __restrict__ csr_src, int E)
{
    int e = blockIdx.x * 256 + threadIdx.x;
    if (e < E) {
        int pos = atomicAdd(&cursor[dst[e]], 1);
        csr_src[pos] = src[e];
    }
}

// --- attention: one wave per node, lane owns channels (2l, 2l+1). ----------
// K/V fp8 (2 B/lane/row), Q f16. HW cvt decode; f32 accumulate.
__global__ __launch_bounds__(256) void k_attn(
    const f16* __restrict__ Qb, const unsigned char* __restrict__ Kb8,
    const unsigned char* __restrict__ Vb8,
    const int* __restrict__ rowptr, const int* __restrict__ csr_src,
    f16* __restrict__ attnf, int N)
{
    const int node = blockIdx.x * 4 + (threadIdx.x >> 6);
    const int lane = threadIdx.x & 63;
    if (node >= N) return;
    const int beg = rowptr[node], end = rowptr[node + 1];
    const h2 q2 = ((const h2*)(Qb + (size_t)node * 128))[lane];
    const float qx = (float)q2[0], qy = (float)q2[1];
    float axA = 0.f, ayA = 0.f, axB = 0.f, ayB = 0.f, zA = 0.f, zB = 0.f;
    int i = beg;
    for (; i + 3 < end; i += 4) {
        int s0 = csr_src[i], s1 = csr_src[i + 1];
        int s2 = csr_src[i + 2], s3 = csr_src[i + 3];
        unsigned k0 = *(const unsigned short*)(Kb8 + (size_t)s0 * 128 + 2 * lane);
        unsigned k1 = *(const unsigned short*)(Kb8 + (size_t)s1 * 128 + 2 * lane);
        unsigned k2 = *(const unsigned short*)(Kb8 + (size_t)s2 * 128 + 2 * lane);
        unsigned k3 = *(const unsigned short*)(Kb8 + (size_t)s3 * 128 + 2 * lane);
        unsigned v0 = *(const unsigned short*)(Vb8 + (size_t)s0 * 128 + 2 * lane);
        unsigned v1 = *(const unsigned short*)(Vb8 + (size_t)s1 * 128 + 2 * lane);
        unsigned v2 = *(const unsigned short*)(Vb8 + (size_t)s2 * 128 + 2 * lane);
        unsigned v3 = *(const unsigned short*)(Vb8 + (size_t)s3 * 128 + 2 * lane);
        ff2 kf0 = fp8x2_dec(k0), kf1 = fp8x2_dec(k1);
        ff2 kf2 = fp8x2_dec(k2), kf3 = fp8x2_dec(k3);
        float p0 = fmaf(qx, kf0.x, qy * kf0.y);
        float p1 = fmaf(qx, kf1.x, qy * kf1.y);
        float p2 = fmaf(qx, kf2.x, qy * kf2.y);
        float p3 = fmaf(qx, kf3.x, qy * kf3.y);
        p0 += __shfl_xor(p0, 4, 8); p1 += __shfl_xor(p1, 4, 8);
        p2 += __shfl_xor(p2, 4, 8); p3 += __shfl_xor(p3, 4, 8);
        p0 += __shfl_xor(p0, 2, 8); p1 += __shfl_xor(p1, 2, 8);
        p2 += __shfl_xor(p2, 2, 8); p3 += __shfl_xor(p3, 2, 8);
        p0 += __shfl_xor(p0, 1, 8); p1 += __shfl_xor(p1, 1, 8);
        p2 += __shfl_xor(p2, 1, 8); p3 += __shfl_xor(p3, 1, 8);
        float sc0 = __expf(fminf(fmaxf(p0 * 0.25f, -5.f), 5.f));
        float sc1 = __expf(fminf(fmaxf(p1 * 0.25f, -5.f), 5.f));
        float sc2 = __expf(fminf(fmaxf(p2 * 0.25f, -5.f), 5.f));
        float sc3 = __expf(fminf(fmaxf(p3 * 0.25f, -5.f), 5.f));
        ff2 vf0 = fp8x2_dec(v0), vf1 = fp8x2_dec(v1);
        ff2 vf2 = fp8x2_dec(v2), vf3 = fp8x2_dec(v3);
        axA = fmaf(vf0.x, sc0, axA); ayA = fmaf(vf0.y, sc0, ayA);
        axB = fmaf(vf1.x, sc1, axB); ayB = fmaf(vf1.y, sc1, ayB);
        axA = fmaf(vf2.x, sc2, axA); ayA = fmaf(vf2.y, sc2, ayA);
        axB = fmaf(vf3.x, sc3, axB); ayB = fmaf(vf3.y, sc3, ayB);
        zA += sc0 + sc2; zB += sc1 + sc3;
    }
    for (; i < end; ++i) {
        int s0 = csr_src[i];
        unsigned k0 = *(const unsigned short*)(Kb8 + (size_t)s0 * 128 + 2 * lane);
        unsigned v0 = *(const unsigned short*)(Vb8 + (size_t)s0 * 128 + 2 * lane);
        ff2 kf0 = fp8x2_dec(k0);
        float p0 = fmaf(qx, kf0.x, qy * kf0.y);
        p0 += __shfl_xor(p0, 4, 8); p0 += __shfl_xor(p0, 2, 8); p0 += __shfl_xor(p0, 1, 8);
        float sc0 = __expf(fminf(fmaxf(p0 * 0.25f, -5.f), 5.f));
        ff2 vf0 = fp8x2_dec(v0);
        axA = fmaf(vf0.x, sc0, axA); ayA = fmaf(vf0.y, sc0, ayA);
        zA += sc0;
    }
    float inv = 1.f / (zA + zB);
    h2 o2;
    o2[0] = (f16)((axA + axB) * inv);
    o2[1] = (f16)((ayA + ayB) * inv);
    int slab = node >> 7, m = (node >> 4) & 7, lr = node & 15;
    int kb = lane >> 4, quad2 = (lane & 15) >> 2, j = (lane & 3) * 2;
    *(h2*)(attnf + (size_t)slab * ND128 +
           (size_t)(((kb * 8 + m) * 64 + lr + 16 * quad2) * 8 + j)) = o2;
}

// --- O-proj: t1 = attn @ WO^T + h + bO -> f16 frag t1b; BN1 sums. ----------
__global__ __launch_bounds__(256) void k_oproj(
    const f16* __restrict__ attnf, const f16* __restrict__ Wob,
    const float* __restrict__ h, const float* __restrict__ bO,
    f16* __restrict__ t1b, float* __restrict__ bn, int N)
{
    __shared__ float csum[128], csq[128];
    const int tid = threadIdx.x, slab = blockIdx.x;
    const int w = tid >> 6, lane = tid & 63;
    if (tid < 128) { csum[tid] = 0.f; csq[tid] = 0.f; }
    __syncthreads();
    const f16* A = attnf + (size_t)slab * ND128;

    h8 bfr[2][4];
#pragma unroll
    for (int nt = 0; nt < 2; ++nt)
#pragma unroll
        for (int kb = 0; kb < 4; ++kb)
            bfr[nt][kb] = *(const h8*)(Wob + (size_t)(((2 * w + nt) * 4 + kb) * 64 + lane) * 8);

    f4 acc[8][2];
    f4 zero = {0.f, 0.f, 0.f, 0.f};
#pragma unroll
    for (int m = 0; m < 8; ++m) { acc[m][0] = zero; acc[m][1] = zero; }
#pragma unroll
    for (int m = 0; m < 8; ++m) {
#pragma unroll
        for (int kb = 0; kb < 4; ++kb) {
            h8 a = *(const h8*)(A + (size_t)((kb * 8 + m) * 64 + lane) * 8);
            acc[m][0] = __builtin_amdgcn_mfma_f32_16x16x32_f16(bfr[0][kb], a, acc[m][0], 0, 0, 0);
            acc[m][1] = __builtin_amdgcn_mfma_f32_16x16x32_f16(bfr[1][kb], a, acc[m][1], 0, 0, 0);
        }
    }

    const int rl = lane & 15, quad = lane >> 4;
    float4 bo[2];
#pragma unroll
    for (int nt = 0; nt < 2; ++nt)
        bo[nt] = *(const float4*)(bO + w * 32 + nt * 16 + quad * 4);
    float pcs[2][4], pcq[2][4];
#pragma unroll
    for (int nt = 0; nt < 2; ++nt)
#pragma unroll
        for (int r = 0; r < 4; ++r) { pcs[nt][r] = 0.f; pcq[nt][r] = 0.f; }

#pragma unroll
    for (int m = 0; m < 8; ++m) {
        int gr = slab * 128 + m * 16 + rl;
        if (gr < N) {
#pragma unroll
            for (int nt = 0; nt < 2; ++nt) {
                int col0 = w * 32 + nt * 16 + quad * 4;
                float4 hv = *(const float4*)(h + (size_t)gr * 128 + col0);
                float v0 = acc[m][nt][0] + hv.x + bo[nt].x;
                float v1 = acc[m][nt][1] + hv.y + bo[nt].y;
                float v2 = acc[m][nt][2] + hv.z + bo[nt].z;
                float v3 = acc[m][nt][3] + hv.w + bo[nt].w;
                h4 o; o[0] = (f16)v0; o[1] = (f16)v1; o[2] = (f16)v2; o[3] = (f16)v3;
                *(h4*)(t1b + (size_t)slab * ND128 +
                       (size_t)(((w * 8 + m) * 64 + (nt * 2 + (quad >> 1)) * 16 + rl) * 8 +
                                (quad & 1) * 4)) = o;
                pcs[nt][0] += v0; pcq[nt][0] += v0 * v0;
                pcs[nt][1] += v1; pcq[nt][1] += v1 * v1;
                pcs[nt][2] += v2; pcq[nt][2] += v2 * v2;
                pcs[nt][3] += v3; pcq[nt][3] += v3 * v3;
            }
        }
    }
#pragma unroll
    for (int nt = 0; nt < 2; ++nt)
#pragma unroll
        for (int r = 0; r < 4; ++r) {
            float s = pcs[nt][r], q = pcq[nt][r];
            s += __shfl_xor(s, 8, 16); q += __shfl_xor(q, 8, 16);
            s += __shfl_xor(s, 4, 16); q += __shfl_xor(q, 4, 16);
            s += __shfl_xor(s, 2, 16); q += __shfl_xor(q, 2, 16);
            s += __shfl_xor(s, 1, 16); q += __shfl_xor(q, 1, 16);
            if (rl == 0) {
                int cl = w * 32 + nt * 16 + quad * 4 + r;
                atomicAdd(&csum[cl], s);
                atomicAdd(&csq[cl], q);
            }
        }
    __syncthreads();
    if (tid < 128) {
        atomicAdd(bn + tid, csum[tid]);
        atomicAdd(bn + 128 + tid, csq[tid]);
    }
}

// --- fold BN1 into W1/bias. 256 blocks (one per W1 row). -------------------
__global__ __launch_bounds__(128) void k_fold1(
    const float* __restrict__ bn, const float* __restrict__ g1,
    const float* __restrict__ bb1, const float* __restrict__ W1,
    const float* __restrict__ b1, f16* __restrict__ W1b,
    float* __restrict__ badj, float* __restrict__ sfold,
    float* __restrict__ bfold, int N)
{
    const int o = blockIdx.x, i = threadIdx.x;
    float invN = 1.f / (float)N;
    float mu = bn[i] * invN;
    float var = bn[128 + i] * invN - mu * mu;
    float s = g1[i] * rsqrtf(var + 1e-5f);
    float bb = bb1[i] - mu * s;
    if (o == 0) { sfold[i] = s; bfold[i] = bb; }
    float wv = W1[(size_t)o * 128 + i];
    __shared__ float red[128];
    red[i] = wv * bb;
    const int nt = o >> 4, lanelow = o & 15;
    const int kb = i >> 5, quad = (i >> 3) & 3, j = i & 7;
    W1b[(size_t)(((nt * 4 + kb) * 64 + lanelow + 16 * quad) * 8 + j)] = (f16)(wv * s);
    __syncthreads();
#pragma unroll
    for (int off = 64; off; off >>= 1) {
        if (i < off) red[i] += red[i + off];
        __syncthreads();
    }
    if (i == 0) badj[o] = b1[o] + red[0];
}

// --- FFN1: u = relu(t1b @ W1s^T + badj), f16 frag order (K=256 layout). ----
__global__ __launch_bounds__(256) void k_ffn1(
    const f16* __restrict__ t1b, const f16* __restrict__ W1b,
    const float* __restrict__ badj, f16* __restrict__ ub, int N)
{
    const int slab = blockIdx.x, ch = blockIdx.y;
    const int w = threadIdx.x >> 6, lane = threadIdx.x & 63;
    const f16* A = t1b + (size_t)slab * ND128;

    h8 bfr[2][4];
#pragma unroll
    for (int nt = 0; nt < 2; ++nt)
#pragma unroll
        for (int kb = 0; kb < 4; ++kb) {
            int ntg = ch * 8 + 2 * w + nt;
            bfr[nt][kb] = *(const h8*)(W1b + (size_t)((ntg * 4 + kb) * 64 + lane) * 8);
        }

    f4 acc[8][2];
    f4 zero = {0.f, 0.f, 0.f, 0.f};
#pragma unroll
    for (int m = 0; m < 8; ++m) { acc[m][0] = zero; acc[m][1] = zero; }
#pragma unroll
    for (int m = 0; m < 8; ++m) {
#pragma unroll
        for (int kb = 0; kb < 4; ++kb) {
            h8 a = *(const h8*)(A + (size_t)((kb * 8 + m) * 64 + lane) * 8);
            acc[m][0] = __builtin_amdgcn_mfma_f32_16x16x32_f16(bfr[0][kb], a, acc[m][0], 0, 0, 0);
            acc[m][1] = __builtin_amdgcn_mfma_f32_16x16x32_f16(bfr[1][kb], a, acc[m][1], 0, 0, 0);
        }
    }

    const int rl = lane & 15, quad = lane >> 4;
    const int kbu = ch * 4 + w;
    float4 ba[2];
#pragma unroll
    for (int nt = 0; nt < 2; ++nt)
        ba[nt] = *(const float4*)(badj + ch * 128 + w * 32 + nt * 16 + quad * 4);
#pragma unroll
    for (int m = 0; m < 8; ++m) {
        int gr = slab * 128 + m * 16 + rl;
        if (gr < N) {
#pragma unroll
            for (int nt = 0; nt < 2; ++nt) {
                h4 o;
                o[0] = (f16)fmaxf(acc[m][nt][0] + ba[nt].x, 0.f);
                o[1] = (f16)fmaxf(acc[m][nt][1] + ba[nt].y, 0.f);
                o[2] = (f16)fmaxf(acc[m][nt][2] + ba[nt].z, 0.f);
                o[3] = (f16)fmaxf(acc[m][nt][3] + ba[nt].w, 0.f);
                *(h4*)(ub + (size_t)slab * 32768 +
                       (size_t)(((kbu * 8 + m) * 64 + (nt * 2 + (quad >> 1)) * 16 + rl) * 8 +
                                (quad & 1) * 4)) = o;
            }
        }
    }
}

// --- FFN2: t2 = (s1*t1 + b1v + b2) + u @ W2^T; fp32 out; BN2 sums. ---------
__global__ __launch_bounds__(256) void k_ffn2(
    const f16* __restrict__ ub, const f16* __restrict__ W2b,
    const f16* __restrict__ t1b,
    const float* __restrict__ sfold, const float* __restrict__ bfold,
    const float* __restrict__ b2, float* __restrict__ out,
    float* __restrict__ bn, int N)
{
    __shared__ float csum[128], csq[128], sS[128], sB[128];
    const int tid = threadIdx.x, slab = blockIdx.x;
    const int w = tid >> 6, lane = tid & 63;
    if (tid < 128) {
        csum[tid] = 0.f; csq[tid] = 0.f;
        sS[tid] = sfold[tid]; sB[tid] = bfold[tid] + b2[tid];
    }
    __syncthreads();
    const f16* A = ub + (size_t)slab * 32768;
    const f16* T1 = t1b + (size_t)slab * ND128;

    h8 bfr[2][8];
#pragma unroll
    for (int nt = 0; nt < 2; ++nt)
#pragma unroll
        for (int kb = 0; kb < 8; ++kb)
            bfr[nt][kb] = *(const h8*)(W2b + (size_t)(((2 * w + nt) * 8 + kb) * 64 + lane) * 8);

    f4 acc[8][2];
    f4 zero = {0.f, 0.f, 0.f, 0.f};
#pragma unroll
    for (int m = 0; m < 8; ++m) { acc[m][0] = zero; acc[m][1] = zero; }
#pragma unroll
    for (int m = 0; m < 8; ++m) {
#pragma unroll
        for (int kb = 0; kb < 8; ++kb) {
            h8 a = *(const h8*)(A + (size_t)((kb * 8 + m) * 64 + lane) * 8);
            acc[m][0] = __builtin_amdgcn_mfma_f32_16x16x32_f16(bfr[0][kb], a, acc[m][0], 0, 0, 0);
            acc[m][1] = __builtin_amdgcn_mfma_f32_16x16x32_f16(bfr[1][kb], a, acc[m][1], 0, 0, 0);
        }
    }

    const int rl = lane & 15, quad = lane >> 4;
    float pcs[2][4], pcq[2][4];
#pragma unroll
    for (int nt = 0; nt < 2; ++nt)
#pragma unroll
        for (int r = 0; r < 4; ++r) { pcs[nt][r] = 0.f; pcq[nt][r] = 0.f; }

#pragma unroll
    for (int m = 0; m < 8; ++m) {
        int gr = slab * 128 + m * 16 + rl;
        if (gr < N) {
#pragma unroll
            for (int nt = 0; nt < 2; ++nt) {
                int col0 = w * 32 + nt * 16 + quad * 4;
                h4 t1v = *(const h4*)(T1 +
                    (size_t)(((w * 8 + m) * 64 + (nt * 2 + (quad >> 1)) * 16 + rl) * 8 +
                             (quad & 1) * 4));
                float4 ss = *(const float4*)&sS[col0];
                float4 sb = *(const float4*)&sB[col0];
                float4 o;
                o.x = acc[m][nt][0] + fmaf(ss.x, (float)t1v[0], sb.x);
                o.y = acc[m][nt][1] + fmaf(ss.y, (float)t1v[1], sb.y);
                o.z = acc[m][nt][2] + fmaf(ss.z, (float)t1v[2], sb.z);
                o.w = acc[m][nt][3] + fmaf(ss.w, (float)t1v[3], sb.w);
                *(float4*)(out + (size_t)gr * 128 + col0) = o;
                pcs[nt][0] += o.x; pcq[nt][0] += o.x * o.x;
                pcs[nt][1] += o.y; pcq[nt][1] += o.y * o.y;
                pcs[nt][2] += o.z; pcq[nt][2] += o.z * o.z;
                pcs[nt][3] += o.w; pcq[nt][3] += o.w * o.w;
            }
        }
    }
#pragma unroll
    for (int nt = 0; nt < 2; ++nt)
#pragma unroll
        for (int r = 0; r < 4; ++r) {
            float s = pcs[nt][r], q = pcq[nt][r];
            s += __shfl_xor(s, 8, 16); q += __shfl_xor(q, 8, 16);
            s += __shfl_xor(s, 4, 16); q += __shfl_xor(q, 4, 16);
            s += __shfl_xor(s, 2, 16); q += __shfl_xor(q, 2, 16);
            s += __shfl_xor(s, 1, 16); q += __shfl_xor(q, 1, 16);
            if (rl == 0) {
                int cl = w * 32 + nt * 16 + quad * 4 + r;
                atomicAdd(&csum[cl], s);
                atomicAdd(&csq[cl], q);
            }
        }
    __syncthreads();
    if (tid < 128) {
        atomicAdd(bn + 256 + tid, csum[tid]);
        atomicAdd(bn + 384 + tid, csq[tid]);
    }
}

// --- BN2 normalize in place ------------------------------------------------
__global__ __launch_bounds__(256) void k_bn2(
    float* __restrict__ out, const float* __restrict__ bn,
    const float* __restrict__ g2, const float* __restrict__ bb2, int N)
{
    __shared__ float sS[128], sB[128];
    const int tid = threadIdx.x;
    if (tid < 128) {
        float invN = 1.f / (float)N;
        float mu = bn[256 + tid] * invN;
        float var = bn[384 + tid] * invN - mu * mu;
        float scl = g2[tid] * rsqrtf(var + 1e-5f);
        sS[tid] = scl;
        sB[tid] = bb2[tid] - mu * scl;
    }
    __syncthreads();
    size_t idx = (size_t)blockIdx.x * 256 + tid;
    size_t total = (size_t)N * 32;
    if (idx < total) {
        int c0 = (int)((idx * 4) & 127);
        float4 v = *(const float4*)(out + idx * 4);
        v.x = fmaf(v.x, sS[c0 + 0], sB[c0 + 0]);
        v.y = fmaf(v.y, sS[c0 + 1], sB[c0 + 1]);
        v.z = fmaf(v.z, sS[c0 + 2], sB[c0 + 2]);
        v.w = fmaf(v.w, sS[c0 + 3], sB[c0 + 3]);
        *(float4*)(out + idx * 4) = v;
    }
}

extern "C" void kernel_launch(void* const* d_in, const int* in_sizes, int n_in,
                              void* d_out, int out_size, void* d_ws, size_t ws_size,
                              hipStream_t stream)
{
    const float* h   = (const float*)d_in[0];
    const int*   src = (const int*)d_in[1];
    const int*   dst = (const int*)d_in[2];
    const float* WQ  = (const float*)d_in[3];
    const float* WK  = (const float*)d_in[4];
    const float* WV  = (const float*)d_in[5];
    const float* WO  = (const float*)d_in[6];
    const float* bO  = (const float*)d_in[7];
    const float* W1  = (const float*)d_in[8];
    const float* b1  = (const float*)d_in[9];
    const float* W2  = (const float*)d_in[10];
    const float* b2  = (const float*)d_in[11];
    const float* g1  = (const float*)d_in[12];
    const float* bb1 = (const float*)d_in[13];
    const float* g2  = (const float*)d_in[14];
    const float* bb2 = (const float*)d_in[15];
    float* out = (float*)d_out;

    int N = in_sizes[0] / 128;
    int E = in_sizes[1];
    const int slabs = (N + 127) / 128;
    const int nsb = (N + 2047) / 2048;         // scan blocks (~25)
    const size_t B1 = (size_t)slabs * 32768;   // bytes of one f16 N_pad x 128 buffer

    char* Wp = (char*)d_ws;
    f16* attnf = (f16*)Wp;                           // region 0 (B1)
    f16* Qb  = (f16*)(Wp + B1);                      // B1
    unsigned char* Kb8 = (unsigned char*)(Wp + 2 * B1);        // B1/2
    unsigned char* Vb8 = (unsigned char*)(Wp + 2 * B1 + B1 / 2); // B1/2
    f16* ub  = (f16*)(Wp + B1);                      // 2*B1, overlays Qb/Kb8/Vb8 after attn
    f16* t1b = (f16*)(Wp + 3 * B1);                  // B1
    const size_t base = 4 * B1;
    f16* Wqb = (f16*)(Wp + base);
    f16* Wkb = (f16*)(Wp + base + 32768);
    f16* Wvb = (f16*)(Wp + base + 65536);
    f16* Wob = (f16*)(Wp + base + 98304);
    f16* W1b = (f16*)(Wp + base + 131072);
    f16* W2b = (f16*)(Wp + base + 196608);
    float* badj  = (float*)(Wp + base + 262144);
    float* sfold = (float*)(Wp + base + 263168);
    float* bfold = (float*)(Wp + base + 263680);
    float* bn    = (float*)(Wp + base + 264192);     // 512 floats (zeroed in prep)
    int* cursor  = (int*)(Wp + base + 266240);       // N ints (zeroed in qkvF)
    int* rowptr  = (int*)(Wp + base + 266240 + (size_t)N * 4);
    int* csr     = (int*)(Wp + base + 266240 + (size_t)N * 8 + 8);
    int* bsum    = (int*)((char*)csr + (size_t)E * 4);

    k_prep<<<6, 256, 0, stream>>>(WQ, WK, WV, WO, W2, Wqb, Wkb, Wvb, Wob, W2b, bn);
    k_qkvF<<<slabs, 256, 0, stream>>>(h, Wqb, Wkb, Wvb, Qb, Kb8, Vb8, cursor, N);
    k_hist<<<(E + 255) / 256, 256, 0, stream>>>(dst, cursor, E);
    k_scanA<<<nsb, 256, 0, stream>>>(cursor, bsum, N);
    k_scanC<<<nsb, 256, 0, stream>>>(cursor, bsum, rowptr, cursor, N, nsb);
    k_scatter<<<(E + 255) / 256, 256, 0, stream>>>(src, dst, cursor, csr, E);
    k_attn<<<(N + 3) / 4, 256, 0, stream>>>(Qb, Kb8, Vb8, rowptr, csr, attnf, N);
    k_oproj<<<slabs, 256, 0, stream>>>(attnf, Wob, h, bO, t1b, bn, N);
    k_fold1<<<256, 128, 0, stream>>>(bn, g1, bb1, W1, b1, W1b, badj, sfold, bfold, N);
    k_ffn1<<<dim3(slabs, 2), 256, 0, stream>>>(t1b, W1b, badj, ub, N);
    k_ffn2<<<slabs, 256, 0, stream>>>(ub, W2b, t1b, sfold, bfold, b2, out, bn, N);
    k_bn2<<<(int)(((size_t)N * 32 + 255) / 256), 256, 0, stream>>>(out, bn, g2, bb2, N);
}

// Round 11
// 322.323 us; speedup vs baseline: 1.0324x; 1.0324x over previous
//
#include <hip/hip_runtime.h>
#include <math.h>

// ---------------------------------------------------------------------------
// GraphTransformerLayer N=50000, E=640000, D=128, H=8, DH=16  (gfx950)
// Round 11: round-9 split prep/qkv structure (occupancy!) + round-10 fp8 K/V.
// Round-10's fused qkvF held 128 VGPRs of A-frags -> 144 VGPR, 7% occupancy,
// 50 us. Un-fused: A streams from f16 hb, grid (slabs,3), fp8 pack epilogue.
//
// Fragment order for an MxK slab (M=128, K=KB*32):
//   elem index = ((kb*8 + mtile)*64 + lane)*8 + j
//   row = mtile*16 + (lane&15),  col = kb*32 + (lane>>4)*8 + j
// Swapped-operand MFMA: mfma(Wfrag, hfrag) -> C^T: row = m*16+(lane&15),
// cols = w*32+nt*16+quad*4+{0..3} contiguous.
// ---------------------------------------------------------------------------

#define ND128 16384
typedef _Float16 f16;
typedef __attribute__((ext_vector_type(8))) _Float16 h8;
typedef __attribute__((ext_vector_type(4))) _Float16 h4;
typedef __attribute__((ext_vector_type(2))) _Float16 h2;
typedef __attribute__((ext_vector_type(4))) float f4;
typedef __attribute__((ext_vector_type(2))) float ff2;

__device__ __forceinline__ ff2 fp8x2_dec(unsigned v) {
#if __has_builtin(__builtin_amdgcn_cvt_pk_f32_fp8)
    return __builtin_amdgcn_cvt_pk_f32_fp8((int)v, false);
#else
    ff2 r;
    unsigned b0 = v & 0xffu, b1 = (v >> 8) & 0xffu;
    {
        unsigned e = (b0 >> 3) & 15u, m = b0 & 7u;
        float x = e ? __uint_as_float(((e + 120u) << 23) | (m << 20)) : (float)m * 0.001953125f;
        r.x = (b0 & 0x80u) ? -x : x;
    }
    {
        unsigned e = (b1 >> 3) & 15u, m = b1 & 7u;
        float x = e ? __uint_as_float(((e + 120u) << 23) | (m << 20)) : (float)m * 0.001953125f;
        r.y = (b1 & 0x80u) ? -x : x;
    }
    return r;
#endif
}

#if !__has_builtin(__builtin_amdgcn_cvt_pk_fp8_f32)
__device__ __forceinline__ unsigned char fp8_1(float f) {
    float a = fabsf(f);
    unsigned sg = (__float_as_uint(f) >> 31) << 7;
    if (a >= 448.f) return (unsigned char)(sg | 0x7E);
    if (a < 0.0009765625f) return (unsigned char)sg;
    int E; float m = frexpf(a, &E);
    if (E - 1 < -6) {
        int q = (int)rintf(a * 512.f);
        if (q > 7) return (unsigned char)(sg | 0x08);
        return (unsigned char)(sg | q);
    }
    int q = (int)rintf(m * 16.f);
    if (q == 16) { q = 8; E += 1; }
    int Ef = E - 1 + 7;
    if (Ef > 15) return (unsigned char)(sg | 0x7E);
    return (unsigned char)(sg | (Ef << 3) | (q - 8));
}
#endif

__device__ __forceinline__ unsigned fp8_pack4(float a0, float a1, float a2, float a3) {
#if __has_builtin(__builtin_amdgcn_cvt_pk_fp8_f32)
    int pk = __builtin_amdgcn_cvt_pk_fp8_f32(a0, a1, 0, false);
    pk = __builtin_amdgcn_cvt_pk_fp8_f32(a2, a3, pk, true);
    return (unsigned)pk;
#else
    return (unsigned)fp8_1(a0) | ((unsigned)fp8_1(a1) << 8) |
           ((unsigned)fp8_1(a2) << 16) | ((unsigned)fp8_1(a3) << 24);
#endif
}

// --- prep: cast h -> hb (frag order); blocks 0-5 also cast weights;
// block 6 zeroes bn; every block zeroes its 128-int slice of cursor. --------
__global__ __launch_bounds__(256) void k_prep(
    const float* __restrict__ h, f16* __restrict__ hb,
    const float* __restrict__ WQ, const float* __restrict__ WK,
    const float* __restrict__ WV, const float* __restrict__ WO,
    const float* __restrict__ W2,
    f16* __restrict__ Wqb, f16* __restrict__ Wkb,
    f16* __restrict__ Wvb, f16* __restrict__ Wob, f16* __restrict__ W2b,
    float* __restrict__ bn, int* __restrict__ cursor, int N)
{
    const int slab = blockIdx.x;
    const int tid = threadIdx.x;
    if (tid < 128) {
        int ci = slab * 128 + tid;
        if (ci < N) cursor[ci] = 0;
    }
    if (slab == 6) { bn[tid] = 0.f; bn[tid + 256] = 0.f; }
#pragma unroll
    for (int it = 0; it < 8; ++it) {
        int cid = it * 256 + tid;              // 0..2047
        int lane = cid & 63;
        int m = (cid >> 6) & 7;
        int kb = cid >> 9;
        int row = slab * 128 + m * 16 + (lane & 15);
        int col = kb * 32 + (lane >> 4) * 8;
        f16 o8[8];
        if (row < N) {
            const float* p = h + (size_t)row * 128 + col;
            float4 f0 = *(const float4*)p;
            float4 f1 = *(const float4*)(p + 4);
            o8[0] = (f16)f0.x; o8[1] = (f16)f0.y; o8[2] = (f16)f0.z; o8[3] = (f16)f0.w;
            o8[4] = (f16)f1.x; o8[5] = (f16)f1.y; o8[6] = (f16)f1.z; o8[7] = (f16)f1.w;
        } else {
#pragma unroll
            for (int j = 0; j < 8; ++j) o8[j] = (f16)0.f;
        }
        *(h8*)(hb + (size_t)slab * ND128 + (size_t)cid * 8) = *(const h8*)o8;
    }
    if (slab < 6) {
        const float* Wsrc; f16* dst; int K, base;
        if (slab < 4) {
            Wsrc = slab == 0 ? WQ : slab == 1 ? WK : slab == 2 ? WV : WO;
            dst  = slab == 0 ? Wqb : slab == 1 ? Wkb : slab == 2 ? Wvb : Wob;
            K = 128; base = 0;
        } else {
            Wsrc = W2; dst = W2b; K = 256; base = (slab - 4) * 2048;
        }
#pragma unroll
        for (int it = 0; it < 8; ++it) {
            int cid = base + it * 256 + tid;
            int lane = cid & 63;
            int kb, nt;
            if (K == 128) { kb = (cid >> 6) & 3; nt = cid >> 8; }
            else          { kb = (cid >> 6) & 7; nt = cid >> 9; }
            int row = nt * 16 + (lane & 15);
            int col = kb * 32 + (lane >> 4) * 8;
            const float* p = Wsrc + (size_t)row * K + col;
            f16 o8[8];
#pragma unroll
            for (int j = 0; j < 8; ++j) o8[j] = (f16)p[j];
            *(h8*)(dst + (size_t)cid * 8) = *(const h8*)o8;
        }
    }
}

// --- QKV: grid (slabs, 3). A streams from hb; Q f16 rows, K/V fp8 rows. ----
__global__ __launch_bounds__(256) void k_qkv(
    const f16* __restrict__ hb, const f16* __restrict__ Wqb,
    const f16* __restrict__ Wkb, const f16* __restrict__ Wvb,
    f16* __restrict__ Qb, unsigned char* __restrict__ Kb8,
    unsigned char* __restrict__ Vb8, int N)
{
    const int slab = blockIdx.x, oidx = blockIdx.y;
    const int w = threadIdx.x >> 6, lane = threadIdx.x & 63;
    const f16* __restrict__ Wb = oidx == 0 ? Wqb : oidx == 1 ? Wkb : Wvb;
    const f16* A = hb + (size_t)slab * ND128;

    h8 bfr[2][4];
#pragma unroll
    for (int nt = 0; nt < 2; ++nt)
#pragma unroll
        for (int kb = 0; kb < 4; ++kb)
            bfr[nt][kb] = *(const h8*)(Wb + (size_t)(((2 * w + nt) * 4 + kb) * 64 + lane) * 8);

    f4 acc[8][2];
    f4 zero = {0.f, 0.f, 0.f, 0.f};
#pragma unroll
    for (int m = 0; m < 8; ++m) { acc[m][0] = zero; acc[m][1] = zero; }

#pragma unroll
    for (int m = 0; m < 8; ++m) {
#pragma unroll
        for (int kb = 0; kb < 4; ++kb) {
            h8 a = *(const h8*)(A + (size_t)((kb * 8 + m) * 64 + lane) * 8);
            acc[m][0] = __builtin_amdgcn_mfma_f32_16x16x32_f16(bfr[0][kb], a, acc[m][0], 0, 0, 0);
            acc[m][1] = __builtin_amdgcn_mfma_f32_16x16x32_f16(bfr[1][kb], a, acc[m][1], 0, 0, 0);
        }
    }

    const int rl = lane & 15, quad = lane >> 4;
    if (oidx == 0) {
#pragma unroll
        for (int m = 0; m < 8; ++m) {
            int gr = slab * 128 + m * 16 + rl;
            if (gr < N) {
#pragma unroll
                for (int nt = 0; nt < 2; ++nt) {
                    h4 o;
                    o[0] = (f16)acc[m][nt][0]; o[1] = (f16)acc[m][nt][1];
                    o[2] = (f16)acc[m][nt][2]; o[3] = (f16)acc[m][nt][3];
                    *(h4*)(Qb + (size_t)gr * 128 + w * 32 + nt * 16 + quad * 4) = o;
                }
            }
        }
    } else {
        unsigned char* __restrict__ O8 = oidx == 1 ? Kb8 : Vb8;
#pragma unroll
        for (int m = 0; m < 8; ++m) {
            int gr = slab * 128 + m * 16 + rl;
            if (gr < N) {
#pragma unroll
                for (int nt = 0; nt < 2; ++nt) {
                    unsigned pk = fp8_pack4(acc[m][nt][0], acc[m][nt][1],
                                            acc[m][nt][2], acc[m][nt][3]);
                    *(unsigned*)(O8 + (size_t)gr * 128 + w * 32 + nt * 16 + quad * 4) = pk;
                }
            }
        }
    }
}

// --- CSR build -------------------------------------------------------------
__global__ __launch_bounds__(256) void k_hist(
    const int* __restrict__ dst, int* __restrict__ cursor, int E)
{
    int e = blockIdx.x * 256 + threadIdx.x;
    if (e < E) atomicAdd(&cursor[dst[e]], 1);
}

__global__ __launch_bounds__(256) void k_scanA(
    const int* __restrict__ cnt, int* __restrict__ bsum, int N)
{
    const int t = threadIdx.x;
    int base = blockIdx.x * 2048 + t * 8;
    int s = 0;
#pragma unroll
    for (int j = 0; j < 8; ++j) {
        int idx = base + j;
        if (idx < N) s += cnt[idx];
    }
#pragma unroll
    for (int off = 32; off; off >>= 1) s += __shfl_down(s, off, 64);
    __shared__ int ws4[4];
    if ((t & 63) == 0) ws4[t >> 6] = s;
    __syncthreads();
    if (t == 0) bsum[blockIdx.x] = ws4[0] + ws4[1] + ws4[2] + ws4[3];
}

__global__ __launch_bounds__(256) void k_scanC(
    const int* __restrict__ cnt, const int* __restrict__ bsum,
    int* __restrict__ rowptr, int* __restrict__ cursor, int N, int nsb)
{
    const int t = threadIdx.x, b = blockIdx.x;
    __shared__ int sboff;
    if (t == 0) {
        int r = 0;
        for (int i2 = 0; i2 < b; ++i2) r += bsum[i2];
        sboff = r;
    }
    if (t == 64 && b == nsb - 1) {
        int r = 0;
        for (int i2 = 0; i2 < nsb; ++i2) r += bsum[i2];
        rowptr[N] = r;
    }
    int base = b * 2048 + t * 8;
    int loc[8];
    int s = 0;
#pragma unroll
    for (int j = 0; j < 8; ++j) {
        int idx = base + j;
        loc[j] = (idx < N) ? cnt[idx] : 0;
        s += loc[j];
    }
    __shared__ int part[256];
    part[t] = s;
    __syncthreads();
    for (int off = 1; off < 256; off <<= 1) {
        int v = (t >= off) ? part[t - off] : 0;
        __syncthreads();
        part[t] += v;
        __syncthreads();
    }
    int run = sboff + (t ? part[t - 1] : 0);
#pragma unroll
    for (int j = 0; j < 8; ++j) {
        int idx = base + j;
        if (idx < N) { rowptr[idx] = run; cursor[idx] = run; run += loc[j]; }
    }
}

__global__ __launch_bounds__(256) void k_scatter(
    const int* __restrict__ src, const int* __restrict__ dst,
    int* __restrict__ cursor, int* __restrict__ csr_src, int E)
{
    int e = blockIdx.x * 256 + threadIdx.x;
    if (e < E) {
        int pos = atomicAdd(&cursor[dst[e]], 1);
        csr_src[pos] = src[e];
    }
}

// --- attention: one wave per node, lane owns channels (2l, 2l+1). ----------
// K/V fp8 (2 B/lane/row), Q f16. HW cvt decode; f32 accumulate.
__global__ __launch_bounds__(256) void k_attn(
    const f16* __restrict__ Qb, const unsigned char* __restrict__ Kb8,
    const unsigned char* __restrict__ Vb8,
    const int* __restrict__ rowptr, const int* __restrict__ csr_src,
    f16* __restrict__ attnf, int N)
{
    const int node = blockIdx.x * 4 + (threadIdx.x >> 6);
    const int lane = threadIdx.x & 63;
    if (node >= N) return;
    const int beg = rowptr[node], end = rowptr[node + 1];
    const h2 q2 = ((const h2*)(Qb + (size_t)node * 128))[lane];
    const float qx = (float)q2[0], qy = (float)q2[1];
    float axA = 0.f, ayA = 0.f, axB = 0.f, ayB = 0.f, zA = 0.f, zB = 0.f;
    int i = beg;
    for (; i + 3 < end; i += 4) {
        int s0 = csr_src[i], s1 = csr_src[i + 1];
        int s2 = csr_src[i + 2], s3 = csr_src[i + 3];
        unsigned k0 = *(const unsigned short*)(Kb8 + (size_t)s0 * 128 + 2 * lane);
        unsigned k1 = *(const unsigned short*)(Kb8 + (size_t)s1 * 128 + 2 * lane);
        unsigned k2 = *(const unsigned short*)(Kb8 + (size_t)s2 * 128 + 2 * lane);
        unsigned k3 = *(const unsigned short*)(Kb8 + (size_t)s3 * 128 + 2 * lane);
        unsigned v0 = *(const unsigned short*)(Vb8 + (size_t)s0 * 128 + 2 * lane);
        unsigned v1 = *(const unsigned short*)(Vb8 + (size_t)s1 * 128 + 2 * lane);
        unsigned v2 = *(const unsigned short*)(Vb8 + (size_t)s2 * 128 + 2 * lane);
        unsigned v3 = *(const unsigned short*)(Vb8 + (size_t)s3 * 128 + 2 * lane);
        ff2 kf0 = fp8x2_dec(k0), kf1 = fp8x2_dec(k1);
        ff2 kf2 = fp8x2_dec(k2), kf3 = fp8x2_dec(k3);
        float p0 = fmaf(qx, kf0.x, qy * kf0.y);
        float p1 = fmaf(qx, kf1.x, qy * kf1.y);
        float p2 = fmaf(qx, kf2.x, qy * kf2.y);
        float p3 = fmaf(qx, kf3.x, qy * kf3.y);
        p0 += __shfl_xor(p0, 4, 8); p1 += __shfl_xor(p1, 4, 8);
        p2 += __shfl_xor(p2, 4, 8); p3 += __shfl_xor(p3, 4, 8);
        p0 += __shfl_xor(p0, 2, 8); p1 += __shfl_xor(p1, 2, 8);
        p2 += __shfl_xor(p2, 2, 8); p3 += __shfl_xor(p3, 2, 8);
        p0 += __shfl_xor(p0, 1, 8); p1 += __shfl_xor(p1, 1, 8);
        p2 += __shfl_xor(p2, 1, 8); p3 += __shfl_xor(p3, 1, 8);
        float sc0 = __expf(fminf(fmaxf(p0 * 0.25f, -5.f), 5.f));
        float sc1 = __expf(fminf(fmaxf(p1 * 0.25f, -5.f), 5.f));
        float sc2 = __expf(fminf(fmaxf(p2 * 0.25f, -5.f), 5.f));
        float sc3 = __expf(fminf(fmaxf(p3 * 0.25f, -5.f), 5.f));
        ff2 vf0 = fp8x2_dec(v0), vf1 = fp8x2_dec(v1);
        ff2 vf2 = fp8x2_dec(v2), vf3 = fp8x2_dec(v3);
        axA = fmaf(vf0.x, sc0, axA); ayA = fmaf(vf0.y, sc0, ayA);
        axB = fmaf(vf1.x, sc1, axB); ayB = fmaf(vf1.y, sc1, ayB);
        axA = fmaf(vf2.x, sc2, axA); ayA = fmaf(vf2.y, sc2, ayA);
        axB = fmaf(vf3.x, sc3, axB); ayB = fmaf(vf3.y, sc3, ayB);
        zA += sc0 + sc2; zB += sc1 + sc3;
    }
    for (; i < end; ++i) {
        int s0 = csr_src[i];
        unsigned k0 = *(const unsigned short*)(Kb8 + (size_t)s0 * 128 + 2 * lane);
        unsigned v0 = *(const unsigned short*)(Vb8 + (size_t)s0 * 128 + 2 * lane);
        ff2 kf0 = fp8x2_dec(k0);
        float p0 = fmaf(qx, kf0.x, qy * kf0.y);
        p0 += __shfl_xor(p0, 4, 8); p0 += __shfl_xor(p0, 2, 8); p0 += __shfl_xor(p0, 1, 8);
        float sc0 = __expf(fminf(fmaxf(p0 * 0.25f, -5.f), 5.f));
        ff2 vf0 = fp8x2_dec(v0);
        axA = fmaf(vf0.x, sc0, axA); ayA = fmaf(vf0.y, sc0, ayA);
        zA += sc0;
    }
    float inv = 1.f / (zA + zB);
    h2 o2;
    o2[0] = (f16)((axA + axB) * inv);
    o2[1] = (f16)((ayA + ayB) * inv);
    int slab = node >> 7, m = (node >> 4) & 7, lr = node & 15;
    int kb = lane >> 4, quad2 = (lane & 15) >> 2, j = (lane & 3) * 2;
    *(h2*)(attnf + (size_t)slab * ND128 +
           (size_t)(((kb * 8 + m) * 64 + lr + 16 * quad2) * 8 + j)) = o2;
}

// --- O-proj: t1 = attn @ WO^T + h + bO -> f16 frag t1b; BN1 sums. ----------
__global__ __launch_bounds__(256) void k_oproj(
    const f16* __restrict__ attnf, const f16* __restrict__ Wob,
    const float* __restrict__ h, const float* __restrict__ bO,
    f16* __restrict__ t1b, float* __restrict__ bn, int N)
{
    __shared__ float csum[128], csq[128];
    const int tid = threadIdx.x, slab = blockIdx.x;
    const int w = tid >> 6, lane = tid & 63;
    if (tid < 128) { csum[tid] = 0.f; csq[tid] = 0.f; }
    __syncthreads();
    const f16* A = attnf + (size_t)slab * ND128;

    h8 bfr[2][4];
#pragma unroll
    for (int nt = 0; nt < 2; ++nt)
#pragma unroll
        for (int kb = 0; kb < 4; ++kb)
            bfr[nt][kb] = *(const h8*)(Wob + (size_t)(((2 * w + nt) * 4 + kb) * 64 + lane) * 8);

    f4 acc[8][2];
    f4 zero = {0.f, 0.f, 0.f, 0.f};
#pragma unroll
    for (int m = 0; m < 8; ++m) { acc[m][0] = zero; acc[m][1] = zero; }
#pragma unroll
    for (int m = 0; m < 8; ++m) {
#pragma unroll
        for (int kb = 0; kb < 4; ++kb) {
            h8 a = *(const h8*)(A + (size_t)((kb * 8 + m) * 64 + lane) * 8);
            acc[m][0] = __builtin_amdgcn_mfma_f32_16x16x32_f16(bfr[0][kb], a, acc[m][0], 0, 0, 0);
            acc[m][1] = __builtin_amdgcn_mfma_f32_16x16x32_f16(bfr[1][kb], a, acc[m][1], 0, 0, 0);
        }
    }

    const int rl = lane & 15, quad = lane >> 4;
    float4 bo[2];
#pragma unroll
    for (int nt = 0; nt < 2; ++nt)
        bo[nt] = *(const float4*)(bO + w * 32 + nt * 16 + quad * 4);
    float pcs[2][4], pcq[2][4];
#pragma unroll
    for (int nt = 0; nt < 2; ++nt)
#pragma unroll
        for (int r = 0; r < 4; ++r) { pcs[nt][r] = 0.f; pcq[nt][r] = 0.f; }

#pragma unroll
    for (int m = 0; m < 8; ++m) {
        int gr = slab * 128 + m * 16 + rl;
        if (gr < N) {
#pragma unroll
            for (int nt = 0; nt < 2; ++nt) {
                int col0 = w * 32 + nt * 16 + quad * 4;
                float4 hv = *(const float4*)(h + (size_t)gr * 128 + col0);
                float v0 = acc[m][nt][0] + hv.x + bo[nt].x;
                float v1 = acc[m][nt][1] + hv.y + bo[nt].y;
                float v2 = acc[m][nt][2] + hv.z + bo[nt].z;
                float v3 = acc[m][nt][3] + hv.w + bo[nt].w;
                h4 o; o[0] = (f16)v0; o[1] = (f16)v1; o[2] = (f16)v2; o[3] = (f16)v3;
                *(h4*)(t1b + (size_t)slab * ND128 +
                       (size_t)(((w * 8 + m) * 64 + (nt * 2 + (quad >> 1)) * 16 + rl) * 8 +
                                (quad & 1) * 4)) = o;
                pcs[nt][0] += v0; pcq[nt][0] += v0 * v0;
                pcs[nt][1] += v1; pcq[nt][1] += v1 * v1;
                pcs[nt][2] += v2; pcq[nt][2] += v2 * v2;
                pcs[nt][3] += v3; pcq[nt][3] += v3 * v3;
            }
        }
    }
#pragma unroll
    for (int nt = 0; nt < 2; ++nt)
#pragma unroll
        for (int r = 0; r < 4; ++r) {
            float s = pcs[nt][r], q = pcq[nt][r];
            s += __shfl_xor(s, 8, 16); q += __shfl_xor(q, 8, 16);
            s += __shfl_xor(s, 4, 16); q += __shfl_xor(q, 4, 16);
            s += __shfl_xor(s, 2, 16); q += __shfl_xor(q, 2, 16);
            s += __shfl_xor(s, 1, 16); q += __shfl_xor(q, 1, 16);
            if (rl == 0) {
                int cl = w * 32 + nt * 16 + quad * 4 + r;
                atomicAdd(&csum[cl], s);
                atomicAdd(&csq[cl], q);
            }
        }
    __syncthreads();
    if (tid < 128) {
        atomicAdd(bn + tid, csum[tid]);
        atomicAdd(bn + 128 + tid, csq[tid]);
    }
}

// --- fold BN1 into W1/bias. 256 blocks (one per W1 row). -------------------
__global__ __launch_bounds__(128) void k_fold1(
    const float* __restrict__ bn, const float* __restrict__ g1,
    const float* __restrict__ bb1, const float* __restrict__ W1,
    const float* __restrict__ b1, f16* __restrict__ W1b,
    float* __restrict__ badj, float* __restrict__ sfold,
    float* __restrict__ bfold, int N)
{
    const int o = blockIdx.x, i = threadIdx.x;
    float invN = 1.f / (float)N;
    float mu = bn[i] * invN;
    float var = bn[128 + i] * invN - mu * mu;
    float s = g1[i] * rsqrtf(var + 1e-5f);
    float bb = bb1[i] - mu * s;
    if (o == 0) { sfold[i] = s; bfold[i] = bb; }
    float wv = W1[(size_t)o * 128 + i];
    __shared__ float red[128];
    red[i] = wv * bb;
    const int nt = o >> 4, lanelow = o & 15;
    const int kb = i >> 5, quad = (i >> 3) & 3, j = i & 7;
    W1b[(size_t)(((nt * 4 + kb) * 64 + lanelow + 16 * quad) * 8 + j)] = (f16)(wv * s);
    __syncthreads();
#pragma unroll
    for (int off = 64; off; off >>= 1) {
        if (i < off) red[i] += red[i + off];
        __syncthreads();
    }
    if (i == 0) badj[o] = b1[o] + red[0];
}

// --- FFN1: u = relu(t1b @ W1s^T + badj), f16 frag order (K=256 layout). ----
__global__ __launch_bounds__(256) void k_ffn1(
    const f16* __restrict__ t1b, const f16* __restrict__ W1b,
    const float* __restrict__ badj, f16* __restrict__ ub, int N)
{
    const int slab = blockIdx.x, ch = blockIdx.y;
    const int w = threadIdx.x >> 6, lane = threadIdx.x & 63;
    const f16* A = t1b + (size_t)slab * ND128;

    h8 bfr[2][4];
#pragma unroll
    for (int nt = 0; nt < 2; ++nt)
#pragma unroll
        for (int kb = 0; kb < 4; ++kb) {
            int ntg = ch * 8 + 2 * w + nt;
            bfr[nt][kb] = *(const h8*)(W1b + (size_t)((ntg * 4 + kb) * 64 + lane) * 8);
        }

    f4 acc[8][2];
    f4 zero = {0.f, 0.f, 0.f, 0.f};
#pragma unroll
    for (int m = 0; m < 8; ++m) { acc[m][0] = zero; acc[m][1] = zero; }
#pragma unroll
    for (int m = 0; m < 8; ++m) {
#pragma unroll
        for (int kb = 0; kb < 4; ++kb) {
            h8 a = *(const h8*)(A + (size_t)((kb * 8 + m) * 64 + lane) * 8);
            acc[m][0] = __builtin_amdgcn_mfma_f32_16x16x32_f16(bfr[0][kb], a, acc[m][0], 0, 0, 0);
            acc[m][1] = __builtin_amdgcn_mfma_f32_16x16x32_f16(bfr[1][kb], a, acc[m][1], 0, 0, 0);
        }
    }

    const int rl = lane & 15, quad = lane >> 4;
    const int kbu = ch * 4 + w;
    float4 ba[2];
#pragma unroll
    for (int nt = 0; nt < 2; ++nt)
        ba[nt] = *(const float4*)(badj + ch * 128 + w * 32 + nt * 16 + quad * 4);
#pragma unroll
    for (int m = 0; m < 8; ++m) {
        int gr = slab * 128 + m * 16 + rl;
        if (gr < N) {
#pragma unroll
            for (int nt = 0; nt < 2; ++nt) {
                h4 o;
                o[0] = (f16)fmaxf(acc[m][nt][0] + ba[nt].x, 0.f);
                o[1] = (f16)fmaxf(acc[m][nt][1] + ba[nt].y, 0.f);
                o[2] = (f16)fmaxf(acc[m][nt][2] + ba[nt].z, 0.f);
                o[3] = (f16)fmaxf(acc[m][nt][3] + ba[nt].w, 0.f);
                *(h4*)(ub + (size_t)slab * 32768 +
                       (size_t)(((kbu * 8 + m) * 64 + (nt * 2 + (quad >> 1)) * 16 + rl) * 8 +
                                (quad & 1) * 4)) = o;
            }
        }
    }
}

// --- FFN2: t2 = (s1*t1 + b1v + b2) + u @ W2^T; fp32 out; BN2 sums. ---------
__global__ __launch_bounds__(256) void k_ffn2(
    const f16* __restrict__ ub, const f16* __restrict__ W2b,
    const f16* __restrict__ t1b,
    const float* __restrict__ sfold, const float* __restrict__ bfold,
    const float* __restrict__ b2, float* __restrict__ out,
    float* __restrict__ bn, int N)
{
    __shared__ float csum[128], csq[128], sS[128], sB[128];
    const int tid = threadIdx.x, slab = blockIdx.x;
    const int w = tid >> 6, lane = tid & 63;
    if (tid < 128) {
        csum[tid] = 0.f; csq[tid] = 0.f;
        sS[tid] = sfold[tid]; sB[tid] = bfold[tid] + b2[tid];
    }
    __syncthreads();
    const f16* A = ub + (size_t)slab * 32768;
    const f16* T1 = t1b + (size_t)slab * ND128;

    h8 bfr[2][8];
#pragma unroll
    for (int nt = 0; nt < 2; ++nt)
#pragma unroll
        for (int kb = 0; kb < 8; ++kb)
            bfr[nt][kb] = *(const h8*)(W2b + (size_t)(((2 * w + nt) * 8 + kb) * 64 + lane) * 8);

    f4 acc[8][2];
    f4 zero = {0.f, 0.f, 0.f, 0.f};
#pragma unroll
    for (int m = 0; m < 8; ++m) { acc[m][0] = zero; acc[m][1] = zero; }
#pragma unroll
    for (int m = 0; m < 8; ++m) {
#pragma unroll
        for (int kb = 0; kb < 8; ++kb) {
            h8 a = *(const h8*)(A + (size_t)((kb * 8 + m) * 64 + lane) * 8);
            acc[m][0] = __builtin_amdgcn_mfma_f32_16x16x32_f16(bfr[0][kb], a, acc[m][0], 0, 0, 0);
            acc[m][1] = __builtin_amdgcn_mfma_f32_16x16x32_f16(bfr[1][kb], a, acc[m][1], 0, 0, 0);
        }
    }

    const int rl = lane & 15, quad = lane >> 4;
    float pcs[2][4], pcq[2][4];
#pragma unroll
    for (int nt = 0; nt < 2; ++nt)
#pragma unroll
        for (int r = 0; r < 4; ++r) { pcs[nt][r] = 0.f; pcq[nt][r] = 0.f; }

#pragma unroll
    for (int m = 0; m < 8; ++m) {
        int gr = slab * 128 + m * 16 + rl;
        if (gr < N) {
#pragma unroll
            for (int nt = 0; nt < 2; ++nt) {
                int col0 = w * 32 + nt * 16 + quad * 4;
                h4 t1v = *(const h4*)(T1 +
                    (size_t)(((w * 8 + m) * 64 + (nt * 2 + (quad >> 1)) * 16 + rl) * 8 +
                             (quad & 1) * 4));
                float4 ss = *(const float4*)&sS[col0];
                float4 sb = *(const float4*)&sB[col0];
                float4 o;
                o.x = acc[m][nt][0] + fmaf(ss.x, (float)t1v[0], sb.x);
                o.y = acc[m][nt][1] + fmaf(ss.y, (float)t1v[1], sb.y);
                o.z = acc[m][nt][2] + fmaf(ss.z, (float)t1v[2], sb.z);
                o.w = acc[m][nt][3] + fmaf(ss.w, (float)t1v[3], sb.w);
                *(float4*)(out + (size_t)gr * 128 + col0) = o;
                pcs[nt][0] += o.x; pcq[nt][0] += o.x * o.x;
                pcs[nt][1] += o.y; pcq[nt][1] += o.y * o.y;
                pcs[nt][2] += o.z; pcq[nt][2] += o.z * o.z;
                pcs[nt][3] += o.w; pcq[nt][3] += o.w * o.w;
            }
        }
    }
#pragma unroll
    for (int nt = 0; nt < 2; ++nt)
#pragma unroll
        for (int r = 0; r < 4; ++r) {
            float s = pcs[nt][r], q = pcq[nt][r];
            s += __shfl_xor(s, 8, 16); q += __shfl_xor(q, 8, 16);
            s += __shfl_xor(s, 4, 16); q += __shfl_xor(q, 4, 16);
            s += __shfl_xor(s, 2, 16); q += __shfl_xor(q, 2, 16);
            s += __shfl_xor(s, 1, 16); q += __shfl_xor(q, 1, 16);
            if (rl == 0) {
                int cl = w * 32 + nt * 16 + quad * 4 + r;
                atomicAdd(&csum[cl], s);
                atomicAdd(&csq[cl], q);
            }
        }
    __syncthreads();
    if (tid < 128) {
        atomicAdd(bn + 256 + tid, csum[tid]);
        atomicAdd(bn + 384 + tid, csq[tid]);
    }
}

// --- BN2 normalize in place ------------------------------------------------
__global__ __launch_bounds__(256) void k_bn2(
    float* __restrict__ out, const float* __restrict__ bn,
    const float* __restrict__ g2, const float* __restrict__ bb2, int N)
{
    __shared__ float sS[128], sB[128];
    const int tid = threadIdx.x;
    if (tid < 128) {
        float invN = 1.f / (float)N;
        float mu = bn[256 + tid] * invN;
        float var = bn[384 + tid] * invN - mu * mu;
        float scl = g2[tid] * rsqrtf(var + 1e-5f);
        sS[tid] = scl;
        sB[tid] = bb2[tid] - mu * scl;
    }
    __syncthreads();
    size_t idx = (size_t)blockIdx.x * 256 + tid;
    size_t total = (size_t)N * 32;
    if (idx < total) {
        int c0 = (int)((idx * 4) & 127);
        float4 v = *(const float4*)(out + idx * 4);
        v.x = fmaf(v.x, sS[c0 + 0], sB[c0 + 0]);
        v.y = fmaf(v.y, sS[c0 + 1], sB[c0 + 1]);
        v.z = fmaf(v.z, sS[c0 + 2], sB[c0 + 2]);
        v.w = fmaf(v.w, sS[c0 + 3], sB[c0 + 3]);
        *(float4*)(out + idx * 4) = v;
    }
}

extern "C" void kernel_launch(void* const* d_in, const int* in_sizes, int n_in,
                              void* d_out, int out_size, void* d_ws, size_t ws_size,
                              hipStream_t stream)
{
    const float* h   = (const float*)d_in[0];
    const int*   src = (const int*)d_in[1];
    const int*   dst = (const int*)d_in[2];
    const float* WQ  = (const float*)d_in[3];
    const float* WK  = (const float*)d_in[4];
    const float* WV  = (const float*)d_in[5];
    const float* WO  = (const float*)d_in[6];
    const float* bO  = (const float*)d_in[7];
    const float* W1  = (const float*)d_in[8];
    const float* b1  = (const float*)d_in[9];
    const float* W2  = (const float*)d_in[10];
    const float* b2  = (const float*)d_in[11];
    const float* g1  = (const float*)d_in[12];
    const float* bb1 = (const float*)d_in[13];
    const float* g2  = (const float*)d_in[14];
    const float* bb2 = (const float*)d_in[15];
    float* out = (float*)d_out;

    int N = in_sizes[0] / 128;
    int E = in_sizes[1];
    const int slabs = (N + 127) / 128;
    const int nsb = (N + 2047) / 2048;         // scan blocks (~25)
    const size_t B1 = (size_t)slabs * 32768;   // bytes of one f16 N_pad x 128 buffer

    char* Wp = (char*)d_ws;
    f16* hb  = (f16*)Wp;                             // becomes attnf after attn
    f16* Qb  = (f16*)(Wp + B1);                      // B1
    unsigned char* Kb8 = (unsigned char*)(Wp + 2 * B1);          // B1/2
    unsigned char* Vb8 = (unsigned char*)(Wp + 2 * B1 + B1 / 2); // B1/2
    f16* ub  = (f16*)(Wp + B1);                      // 2*B1, overlays Qb/Kb8/Vb8 after attn
    f16* t1b = (f16*)(Wp + 3 * B1);                  // B1
    const size_t base = 4 * B1;
    f16* Wqb = (f16*)(Wp + base);
    f16* Wkb = (f16*)(Wp + base + 32768);
    f16* Wvb = (f16*)(Wp + base + 65536);
    f16* Wob = (f16*)(Wp + base + 98304);
    f16* W1b = (f16*)(Wp + base + 131072);
    f16* W2b = (f16*)(Wp + base + 196608);
    float* badj  = (float*)(Wp + base + 262144);
    float* sfold = (float*)(Wp + base + 263168);
    float* bfold = (float*)(Wp + base + 263680);
    float* bn    = (float*)(Wp + base + 264192);     // 512 floats (zeroed in prep)
    int* cursor  = (int*)(Wp + base + 266240);       // N ints (zeroed in prep)
    int* rowptr  = (int*)(Wp + base + 266240 + (size_t)N * 4);
    int* csr     = (int*)(Wp + base + 266240 + (size_t)N * 8 + 8);
    int* bsum    = (int*)((char*)csr + (size_t)E * 4);

    k_prep<<<slabs, 256, 0, stream>>>(h, hb, WQ, WK, WV, WO, W2,
                                      Wqb, Wkb, Wvb, Wob, W2b, bn, cursor, N);
    k_qkv<<<dim3(slabs, 3), 256, 0, stream>>>(hb, Wqb, Wkb, Wvb, Qb, Kb8, Vb8, N);
    k_hist<<<(E + 255) / 256, 256, 0, stream>>>(dst, cursor, E);
    k_scanA<<<nsb, 256, 0, stream>>>(cursor, bsum, N);
    k_scanC<<<nsb, 256, 0, stream>>>(cursor, bsum, rowptr, cursor, N, nsb);
    k_scatter<<<(E + 255) / 256, 256, 0, stream>>>(src, dst, cursor, csr, E);
    k_attn<<<(N + 3) / 4, 256, 0, stream>>>(Qb, Kb8, Vb8, rowptr, csr, hb, N);
    k_oproj<<<slabs, 256, 0, stream>>>(hb, Wob, h, bO, t1b, bn, N);
    k_fold1<<<256, 128, 0, stream>>>(bn, g1, bb1, W1, b1, W1b, badj, sfold, bfold, N);
    k_ffn1<<<dim3(slabs, 2), 256, 0, stream>>>(t1b, W1b, badj, ub, N);
    k_ffn2<<<slabs, 256, 0, stream>>>(ub, W2b, t1b, sfold, bfold, b2, out, bn, N);
    k_bn2<<<(int)(((size_t)N * 32 + 255) / 256), 256, 0, stream>>>(out, bn, g2, bb2, N);
}